// Round 1
// baseline (553.085 us; speedup 1.0000x reference)
//
#include <hip/hip_runtime.h>
#include <stdint.h>

#define NUM_CHARS 128
#define BATCH 8192
#define SEQ 40
#define HIDDEN 256
#define ZDIM 1024 /* 4*HIDDEN */
#define STRIDE_H 264 /* padded bf16 row stride for h in LDS */

typedef __bf16 bf16x8 __attribute__((ext_vector_type(8)));
typedef float floatx16 __attribute__((ext_vector_type(16)));

__device__ __forceinline__ unsigned short f2bf(float f) {
    union { float f; uint32_t u; } v; v.f = f;
    uint32_t u = v.u;
    u += 0x7FFFu + ((u >> 16) & 1u); // RNE
    return (unsigned short)(u >> 16);
}

// ---- prep kernels: repack weights into MFMA-fragment-contiguous layouts ----
// WhFrag[ntile(32)][kk(16)][lane(64)][j(8)] bf16 ; element = Wh[k][n],
// k = kk*16 + (lane>>5)*8 + j, n = ntile*32 + (lane&31)
__global__ void prep_wh(const float* __restrict__ Wh, unsigned short* __restrict__ out) {
    int idx = blockIdx.x * blockDim.x + threadIdx.x; // 0..262143
    int j = idx & 7;
    int lane = (idx >> 3) & 63;
    int kk = (idx >> 9) & 15;
    int ntile = idx >> 13;
    int k = kk * 16 + ((lane >> 5) << 3) + j;
    int n = (ntile << 5) + (lane & 31);
    out[idx] = f2bf(Wh[k * ZDIM + n]);
}

__global__ void prep_wxb(const float* __restrict__ Wx, const float* __restrict__ b,
                         float* __restrict__ out) {
    int idx = blockIdx.x * blockDim.x + threadIdx.x; // 0..131071
    out[idx] = Wx[idx] + b[idx & (ZDIM - 1)];
}

// WdFrag[ntile(4)][kk(16)][lane(64)][j(8)] bf16 ; element = Wd[k][n]
__global__ void prep_wd(const float* __restrict__ Wd, unsigned short* __restrict__ out) {
    int idx = blockIdx.x * blockDim.x + threadIdx.x; // 0..32767
    int j = idx & 7;
    int lane = (idx >> 3) & 63;
    int kk = (idx >> 9) & 15;
    int nt = idx >> 13;
    int k = kk * 16 + ((lane >> 5) << 3) + j;
    int n = (nt << 5) + (lane & 31);
    out[idx] = f2bf(Wd[k * NUM_CHARS + n]);
}

// ---- main kernel: 256 blocks x 512 threads; block owns 32 batch rows ----
__global__ __launch_bounds__(512) void lstm_main(
    const int* __restrict__ inputs, const unsigned short* __restrict__ WhFrag,
    const float* __restrict__ WxB, const unsigned short* __restrict__ WdFrag,
    const float* __restrict__ bd, float* __restrict__ out)
{
    __shared__ int tok[32 * SEQ];                       //  5.1 KB
    __shared__ unsigned short hbuf[2][32 * STRIDE_H];   // 33.8 KB
    __shared__ float logit[32 * NUM_CHARS];             // 16.0 KB

    const int tid = threadIdx.x;
    const int w = tid >> 6;        // wave 0..7, owns h-cols [w*32, w*32+32)
    const int lane = tid & 63;
    const int r0 = blockIdx.x * 32;

    // stage tokens (coalesced: 32 rows x 40 are contiguous in inputs)
    for (int i = tid; i < 32 * SEQ; i += 512) tok[i] = inputs[r0 * SEQ + i];
    // h0 = 0
    for (int i = tid; i < 32 * STRIDE_H; i += 512) hbuf[0][i] = 0;

    // Wh B-fragments, register-resident for all 40 steps.
    // gate g tile covers z-cols (g*8+w)*32 .. +32  == g*256 + w*32 + (lane&31)
    bf16x8 Bf[4][16];
#pragma unroll
    for (int g = 0; g < 4; ++g) {
        int ntile = g * 8 + w;
#pragma unroll
        for (int kk = 0; kk < 16; ++kk)
            Bf[g][kk] = *(const bf16x8*)(WhFrag + (((ntile * 16 + kk) << 6) + lane) * 8);
    }

    floatx16 c_st;
#pragma unroll
    for (int i = 0; i < 16; ++i) c_st[i] = 0.f;

    // C/D layout: col = lane&31, row = (reg&3) + 8*(reg>>2) + 4*(lane>>5)
    int rows[16];
#pragma unroll
    for (int i = 0; i < 16; ++i) rows[i] = (i & 3) + 8 * (i >> 2) + 4 * (lane >> 5);

    __syncthreads();

    const float L2E = 1.4426950408889634f;
    const int abase = (lane & 31) * STRIDE_H + ((lane >> 5) << 3);
    const int hcol = (w << 5) + (lane & 31);
    int cur = 0;

#pragma unroll 1
    for (int t = 0; t < SEQ; ++t) {
        // init acc with gathered Wx[token]+b (fp32) — issued first to hide latency
        int toff[16];
#pragma unroll
        for (int i = 0; i < 16; ++i) toff[i] = tok[rows[i] * SEQ + t] * ZDIM;
        floatx16 acc[4];
#pragma unroll
        for (int g = 0; g < 4; ++g) {
            int col = g * 256 + hcol;
#pragma unroll
            for (int i = 0; i < 16; ++i) acc[g][i] = WxB[toff[i] + col];
        }

        // z += h @ Wh  (A-frags from LDS, B-frags from registers)
        const unsigned short* hb = &hbuf[cur][0];
#pragma unroll
        for (int kk = 0; kk < 16; ++kk) {
            bf16x8 af = *(const bf16x8*)(hb + abase + kk * 16);
            acc[0] = __builtin_amdgcn_mfma_f32_32x32x16_bf16(af, Bf[0][kk], acc[0], 0, 0, 0);
            acc[1] = __builtin_amdgcn_mfma_f32_32x32x16_bf16(af, Bf[1][kk], acc[1], 0, 0, 0);
            acc[2] = __builtin_amdgcn_mfma_f32_32x32x16_bf16(af, Bf[2][kk], acc[2], 0, 0, 0);
            acc[3] = __builtin_amdgcn_mfma_f32_32x32x16_bf16(af, Bf[3][kk], acc[3], 0, 0, 0);
        }

        // gates (keras order i,f,g,o), c fp32 in regs, h -> bf16 LDS (other buffer)
        unsigned short* hn = &hbuf[cur ^ 1][0];
#pragma unroll
        for (int i = 0; i < 16; ++i) {
            float zi = acc[0][i], zf = acc[1][i], zg = acc[2][i], zo = acc[3][i];
            float si = __builtin_amdgcn_rcpf(1.f + __builtin_amdgcn_exp2f(-zi * L2E));
            float sf = __builtin_amdgcn_rcpf(1.f + __builtin_amdgcn_exp2f(-zf * L2E));
            float so = __builtin_amdgcn_rcpf(1.f + __builtin_amdgcn_exp2f(-zo * L2E));
            float tg = 1.f - 2.f * __builtin_amdgcn_rcpf(1.f + __builtin_amdgcn_exp2f(2.f * L2E * zg));
            float c = sf * c_st[i] + si * tg;
            c_st[i] = c;
            float tc = 1.f - 2.f * __builtin_amdgcn_rcpf(1.f + __builtin_amdgcn_exp2f(2.f * L2E * c));
            hn[rows[i] * STRIDE_H + hcol] = f2bf(so * tc);
        }
        __syncthreads();
        cur ^= 1;
    }

    // logits = h @ Wd + bd  (waves 0..3, vocab n-tile = w)
    if (w < 4) {
        floatx16 accd;
        float bdv = bd[(w << 5) + (lane & 31)];
#pragma unroll
        for (int i = 0; i < 16; ++i) accd[i] = bdv;
        const unsigned short* hb = &hbuf[cur][0];
#pragma unroll
        for (int kk = 0; kk < 16; ++kk) {
            bf16x8 af = *(const bf16x8*)(hb + abase + kk * 16);
            bf16x8 bfd = *(const bf16x8*)(WdFrag + (((w * 16 + kk) << 6) + lane) * 8);
            accd = __builtin_amdgcn_mfma_f32_32x32x16_bf16(af, bfd, accd, 0, 0, 0);
        }
#pragma unroll
        for (int i = 0; i < 16; ++i)
            logit[rows[i] * NUM_CHARS + (w << 5) + (lane & 31)] = accd[i];
    }
    __syncthreads();

    // softmax: 16 threads per row (within one wave), 8 cols each
    {
        int row = tid >> 4;
        int c0 = (tid & 15) << 3;
        float v[8];
        float m = -1e30f;
#pragma unroll
        for (int q = 0; q < 8; ++q) { v[q] = logit[row * NUM_CHARS + c0 + q]; m = fmaxf(m, v[q]); }
#pragma unroll
        for (int off = 1; off < 16; off <<= 1) m = fmaxf(m, __shfl_xor(m, off, 16));
        float s = 0.f;
#pragma unroll
        for (int q = 0; q < 8; ++q) { v[q] = __builtin_amdgcn_exp2f((v[q] - m) * L2E); s += v[q]; }
#pragma unroll
        for (int off = 1; off < 16; off <<= 1) s += __shfl_xor(s, off, 16);
        float inv = __builtin_amdgcn_rcpf(s);
        float* op = out + (size_t)(r0 + row) * NUM_CHARS + c0;
#pragma unroll
        for (int q = 0; q < 8; ++q) op[q] = v[q] * inv;
    }
}

extern "C" void kernel_launch(void* const* d_in, const int* in_sizes, int n_in,
                              void* d_out, int out_size, void* d_ws, size_t ws_size,
                              hipStream_t stream) {
    const int*   inputs = (const int*)d_in[0];
    const float* Wx = (const float*)d_in[1];
    const float* Wh = (const float*)d_in[2];
    const float* b  = (const float*)d_in[3];
    const float* Wd = (const float*)d_in[4];
    const float* bd = (const float*)d_in[5];
    float* out = (float*)d_out;

    unsigned short* WhFrag = (unsigned short*)d_ws;                        // 512 KB
    float*          WxB    = (float*)((char*)d_ws + (512 << 10));          // 512 KB
    unsigned short* WdFrag = (unsigned short*)((char*)d_ws + (1024 << 10)); // 64 KB

    prep_wh <<<262144 / 256, 256, 0, stream>>>(Wh, WhFrag);
    prep_wxb<<<131072 / 256, 256, 0, stream>>>(Wx, b, WxB);
    prep_wd <<< 32768 / 256, 256, 0, stream>>>(Wd, WdFrag);
    lstm_main<<<256, 512, 0, stream>>>(inputs, WhFrag, WxB, WdFrag, bd, out);
}